// Round 9
// baseline (729.868 us; speedup 1.0000x reference)
//
#include <hip/hip_runtime.h>
#include <stdint.h>

#define B_   8
#define S_   1024
#define D_   1024
#define H_   16
#define DH_  64
#define N3_  3072

typedef __attribute__((ext_vector_type(16))) float f32x16;
typedef __attribute__((ext_vector_type(8)))  short su8;          // 8 bf16 payload (4 VGPRs)
typedef __attribute__((ext_vector_type(8)))  unsigned short u16x8;
typedef __attribute__((ext_vector_type(4)))  unsigned short u16x4;

__device__ __forceinline__ unsigned short f2bf(float f) {
    union { float f; uint32_t u; } v; v.f = f;
    uint32_t r = v.u + 0x7fffu + ((v.u >> 16) & 1u);   // RNE
    return (unsigned short)(r >> 16);
}
__device__ __forceinline__ unsigned int pk2(float a, float b) {
    return (unsigned int)f2bf(a) | ((unsigned int)f2bf(b) << 16);
}
__device__ __forceinline__ void mfma(f32x16& d, su8 a, su8 b) {
    d = __builtin_amdgcn_mfma_f32_32x32x16_bf16(a, b, d, 0, 0, 0);
}
// C/D layout for 32x32 MFMA: col = lane&31, row = (reg&3) + 8*(reg>>2) + 4*(lane>>5)
__device__ __forceinline__ int rof(int rg, int lb) { return (rg & 3) + 8 * (rg >> 2) + 4 * lb; }

__device__ __forceinline__ void gl_lds(const unsigned short* g, unsigned short* l) {
    __builtin_amdgcn_global_load_lds(
        (const __attribute__((address_space(1))) void*)g,
        (__attribute__((address_space(3))) void*)l, 16, 0, 0);
}

// ---------------- kernel 1: hidden fp32 -> bf16 (linear) ----------------
__global__ __launch_bounds__(256) void cvt_hidden(const float4* __restrict__ src,
                                                  u16x4* __restrict__ dst) {
    int i = blockIdx.x * 256 + threadIdx.x;
    float4 v = src[i];
    u16x4 o;
    o[0] = f2bf(v.x); o[1] = f2bf(v.y); o[2] = f2bf(v.z); o[3] = f2bf(v.w);
    dst[i] = o;
}

// ---------------- kernel 2: W (k,n) fp32 -> Wt (n,k) bf16, LDS tile transpose --
__global__ __launch_bounds__(256) void cvt_w(const float* __restrict__ W,
                                             unsigned short* __restrict__ Wt) {
    __shared__ float tile[64][65];
    int bn = blockIdx.x % 48, bk = blockIdx.x / 48;
    int tr = threadIdx.x >> 4;
    int tc4 = (threadIdx.x & 15) * 4;
#pragma unroll
    for (int p = 0; p < 4; ++p) {
        int r = p * 16 + tr;
        float4 v = *(const float4*)(W + (size_t)(bk * 64 + r) * N3_ + bn * 64 + tc4);
        tile[r][tc4] = v.x; tile[r][tc4 + 1] = v.y; tile[r][tc4 + 2] = v.z; tile[r][tc4 + 3] = v.w;
    }
    __syncthreads();
#pragma unroll
    for (int p = 0; p < 4; ++p) {
        int nr = p * 16 + tr;
        u16x4 o;
        o[0] = f2bf(tile[tc4 + 0][nr]); o[1] = f2bf(tile[tc4 + 1][nr]);
        o[2] = f2bf(tile[tc4 + 2][nr]); o[3] = f2bf(tile[tc4 + 3][nr]);
        *(u16x4*)(Wt + (size_t)(bn * 64 + nr) * 1024 + bk * 64 + tc4) = o;
    }
}

// ---------------- kernel 2b: dist_emb fp32 -> bf16 (2047x64; row 2047 = pad) ---
__global__ __launch_bounds__(256) void cvt_e(const float* __restrict__ de,
                                             unsigned short* __restrict__ Ebf) {
    int i = blockIdx.x * 256 + threadIdx.x;
    if (i < 2047 * 64) Ebf[i] = f2bf(de[i]);
}

// ---------------- kernel 3: QKV GEMM (8192x3072x1024 bf16) ----------------
__global__ __launch_bounds__(256, 2) void gemm_qkv(
    const unsigned short* __restrict__ Ah, const unsigned short* __restrict__ Wt,
    const float* __restrict__ bias, unsigned short* __restrict__ Qw,
    unsigned short* __restrict__ Kw, unsigned short* __restrict__ Vtw) {
    __shared__ unsigned short Asm[2][128 * 64];
    __shared__ unsigned short Bsm[2][128 * 64];
    int tid = threadIdx.x;
    int m0 = (blockIdx.x / 24) * 128;
    int n0 = (blockIdx.x % 24) * 128;
    int w = tid >> 6, lane = tid & 63, li = lane & 31, lb = lane >> 5;
    int wm = w >> 1, wn = w & 1;

    f32x16 acc[2][2];
#pragma unroll
    for (int a = 0; a < 2; ++a)
#pragma unroll
        for (int b = 0; b < 2; ++b)
#pragma unroll
            for (int r = 0; r < 16; ++r) acc[a][b][r] = 0.f;

    int row[4], scol[4], lbase[4];
#pragma unroll
    for (int it = 0; it < 4; ++it) {
        int c = tid + it * 256;
        row[it]  = c >> 3;
        scol[it] = ((c & 7) * 8) ^ ((row[it] & 7) << 3);      // inverse-swizzled source
        lbase[it] = it * 2048 + ((tid >> 6) << 9);
    }

#pragma unroll
    for (int it = 0; it < 4; ++it) {
        gl_lds(Ah + (size_t)(m0 + row[it]) * 1024 + scol[it], &Asm[0][lbase[it]]);
        gl_lds(Wt + (size_t)(n0 + row[it]) * 1024 + scol[it], &Bsm[0][lbase[it]]);
    }
    __syncthreads();

#pragma unroll 1
    for (int t = 0; t < 16; ++t) {
        int buf = t & 1;
        if (t < 15) {
            int kb = (t + 1) * 64;
#pragma unroll
            for (int it = 0; it < 4; ++it) {
                gl_lds(Ah + (size_t)(m0 + row[it]) * 1024 + kb + scol[it], &Asm[buf ^ 1][lbase[it]]);
                gl_lds(Wt + (size_t)(n0 + row[it]) * 1024 + kb + scol[it], &Bsm[buf ^ 1][lbase[it]]);
            }
        }
#pragma unroll
        for (int kk = 0; kk < 4; ++kk) {
            su8 af[2], bf[2];
#pragma unroll
            for (int mt = 0; mt < 2; ++mt) {
                int ar = wm * 64 + mt * 32 + li;
                af[mt] = *(const su8*)(&Asm[buf][ar * 64 + ((kk * 16 + lb * 8) ^ ((ar & 7) << 3))]);
                int br = wn * 64 + mt * 32 + li;
                bf[mt] = *(const su8*)(&Bsm[buf][br * 64 + ((kk * 16 + lb * 8) ^ ((br & 7) << 3))]);
            }
            mfma(acc[0][0], af[0], bf[0]); mfma(acc[0][1], af[0], bf[1]);
            mfma(acc[1][0], af[1], bf[0]); mfma(acc[1][1], af[1], bf[1]);
        }
        __syncthreads();
    }

    // epilogue: Q/K direct (64B-coalesced); V via per-wave LDS transpose -> coalesced rows
    float* tw = (float*)(&Asm[0][0]) + w * 1056;    // 32x33 f32 per wave (Asm free now)
#pragma unroll
    for (int mt = 0; mt < 2; ++mt)
#pragma unroll
        for (int nt = 0; nt < 2; ++nt) {
            int nbase = n0 + wn * 64 + nt * 32;      // 32-aligned: single category
            int cat = (nbase % 192) >> 6;            // 0=Q,1=K,2=V
            int h = nbase / 192;
            int mbase = m0 + wm * 64 + mt * 32;
            size_t bh = (size_t)((mbase >> 10) * 16 + h);
            if (cat < 2) {
#pragma unroll
                for (int rg = 0; rg < 16; ++rg) {
                    int m = mbase + rof(rg, lb);
                    int n = nbase + li;
                    float v = acc[mt][nt][rg] + bias[n];
                    int s = m & 1023;
                    int t3 = n % 192;
                    unsigned short bv = f2bf(v);
                    if (cat == 0) Qw[bh * 65536 + s * 64 + t3] = bv;
                    else          Kw[bh * 65536 + s * 64 + (t3 - 64)] = bv;
                }
            } else {
                int dbase = nbase % 192 - 128;       // 0 or 32
#pragma unroll
                for (int rg = 0; rg < 16; ++rg)
                    tw[rof(rg, lb) * 33 + li] = acc[mt][nt][rg] + bias[nbase + li];
                int sb = (mbase & 1023) + li;
#pragma unroll
                for (int j2 = 0; j2 < 16; ++j2) {
                    int jd = j2 * 2 + lb;
                    float v = tw[li * 33 + jd];
                    Vtw[bh * 65536 + (size_t)(dbase + jd) * 1024 + sb] = f2bf(v);
                }
            }
        }
}

// ---------------- kernel 4: fused attention (3 blocks/CU; E reg-prefetched) ----
// grid = 128 (bh) * 8 (q-blocks of 128 rows); 4 waves, wave = 32 q-rows.
__global__ __launch_bounds__(256, 3) void attn(
    const unsigned short* __restrict__ Qw, const unsigned short* __restrict__ Kw,
    const unsigned short* __restrict__ Vtw, const unsigned short* __restrict__ Ebf,
    const float* __restrict__ mask, float* __restrict__ out) {
    __shared__ unsigned short Ksm[64 * 64];     // 8 KB, swizzled [r][d]
    __shared__ unsigned short Vsm[64 * 64];     // 8 KB, swizzled [d][r]
    __shared__ float Tsm[4][2112];              // 33 KB, per-wave diag buffer (stride 33)
    __shared__ float Msk[64];                   // current-tile mask slice

    int tid = threadIdx.x;
    int bh = blockIdx.x >> 3, qb = blockIdx.x & 7;
    int bb = bh >> 4, h = bh & 15;
    int l0b = qb << 7;
    int w = tid >> 6, lane = tid & 63, li = lane & 31, lb = lane >> 5;
    int l0 = l0b + 32 * w;

    su8 qf[4];
#pragma unroll
    for (int kk = 0; kk < 4; ++kk)
        qf[kk] = *(const su8*)(Qw + (size_t)(bh * 1024 + l0 + li) * 64 + lb * 8 + kk * 16);

    f32x16 cacc[2];
#pragma unroll
    for (int dt = 0; dt < 2; ++dt)
#pragma unroll
        for (int r = 0; r < 16; ++r) cacc[dt][r] = 0.f;
    float m_run = -1e30f, l_run = 0.f;

    // T14 prefetch: K/V/mask for current tile in regs
    u16x8 kpre[2], vpre[2];
    float mpre = 0.f;
    int pc_row[2], pc_o8[2];
#pragma unroll
    for (int it = 0; it < 2; ++it) {
        int c = tid + it * 256;
        pc_row[it] = c >> 3; pc_o8[it] = (c & 7) * 8;
    }
#pragma unroll
    for (int it = 0; it < 2; ++it) {
        kpre[it] = *(const u16x8*)(Kw + (size_t)bh * 65536 + (size_t)pc_row[it] * 64 + pc_o8[it]);
        vpre[it] = *(const u16x8*)(Vtw + (size_t)bh * 65536 + (size_t)pc_row[it] * 1024 + pc_o8[it]);
    }
    if (tid < 64) mpre = mask[bb * 1024 + tid];

    // E fragments for phase (ss=0, t=0), offw = 32w+32
    int E0 = l0b + 960;
    su8 eb[8];
    {
        const unsigned short* ebase = Ebf + ((size_t)(E0 + 32 * w + 32 + li) << 6) + lb * 8;
#pragma unroll
        for (int ct = 0; ct < 2; ++ct)
#pragma unroll
            for (int kk = 0; kk < 4; ++kk)
                eb[ct * 4 + kk] = *(const su8*)(ebase + ct * 2048 + kk * 16);
    }

#pragma unroll 1
    for (int ss = 0; ss < 16; ++ss) {
        int r0s = ss * 64;
        __syncthreads();
#pragma unroll
        for (int it = 0; it < 2; ++it) {
            int row = pc_row[it], o8 = pc_o8[it];
            int lidx = row * 64 + (o8 ^ ((row & 7) << 3));
            *(u16x8*)(&Ksm[lidx]) = kpre[it];
            *(u16x8*)(&Vsm[lidx]) = vpre[it];
        }
        if (tid < 64) Msk[tid] = mpre;
        __syncthreads();
        if (ss < 15) {   // prefetch next tile's K/V/mask
            int r0n = r0s + 64;
#pragma unroll
            for (int it = 0; it < 2; ++it) {
                int row = pc_row[it], o8 = pc_o8[it];
                kpre[it] = *(const u16x8*)(Kw + (size_t)bh * 65536 + (size_t)(r0n + row) * 64 + o8);
                vpre[it] = *(const u16x8*)(Vtw + (size_t)bh * 65536 + (size_t)row * 1024 + r0n + o8);
            }
            if (tid < 64) mpre = mask[bb * 1024 + r0n + tid];
        }

#pragma unroll
        for (int t = 0; t < 2; ++t) {
            su8 kf[4];
#pragma unroll
            for (int kk = 0; kk < 4; ++kk) {
                int kr = 32 * t + li;
                kf[kk] = *(const su8*)(&Ksm[kr * 64 + ((kk * 16 + lb * 8) ^ ((kr & 7) << 3))]);
            }
            f32x16 sa;
#pragma unroll
            for (int r = 0; r < 16; ++r) sa[r] = 0.f;
#pragma unroll
            for (int kk = 0; kk < 4; ++kk) mfma(sa, kf[kk], qf[kk]);   // S^T = K·Q^T

            // T_q: E (regs) · Q -> Tsm (stride 33) -> diagonal gather
#pragma unroll
            for (int ct = 0; ct < 2; ++ct) {
                f32x16 fa;
#pragma unroll
                for (int r = 0; r < 16; ++r) fa[r] = 0.f;
#pragma unroll
                for (int kk = 0; kk < 4; ++kk) mfma(fa, eb[ct * 4 + kk], qf[kk]);
#pragma unroll
                for (int rg = 0; rg < 16; ++rg)
                    Tsm[w][(ct * 32 + rof(rg, lb)) * 33 + li] = fa[rg];
            }
#pragma unroll
            for (int rg = 0; rg < 16; ++rg) {
                int rt = rof(rg, lb);
                sa[rg] += Tsm[w][(li - rt + 31) * 33 + li];
            }
            // T_k: same E fragments · K -> Tsm -> gather
#pragma unroll
            for (int ct = 0; ct < 2; ++ct) {
                f32x16 fa;
#pragma unroll
                for (int r = 0; r < 16; ++r) fa[r] = 0.f;
#pragma unroll
                for (int kk = 0; kk < 4; ++kk) mfma(fa, eb[ct * 4 + kk], kf[kk]);
#pragma unroll
                for (int rg = 0; rg < 16; ++rg)
                    Tsm[w][(ct * 32 + rof(rg, lb)) * 33 + li] = fa[rg];
            }
#pragma unroll
            for (int rg = 0; rg < 16; ++rg) {
                int rt = rof(rg, lb);
                sa[rg] += Tsm[w][(li - rt + 31) * 33 + rt];
            }
            // issue next-phase E loads (eb free after last Tk mfma; latency hides under softmax+PV)
            if (ss < 15 || t == 0) {
                int E0n  = (t == 0) ? E0 : (E0 - 64);
                int offn = (t == 0) ? (32 * w) : (32 * w + 32);
                const unsigned short* ebase = Ebf + ((size_t)(E0n + offn + li) << 6) + lb * 8;
#pragma unroll
                for (int ct = 0; ct < 2; ++ct)
#pragma unroll
                    for (int kk = 0; kk < 4; ++kk)
                        eb[ct * 4 + kk] = *(const su8*)(ebase + ct * 2048 + kk * 16);
            }
            // scale + mask + online softmax with defer-max
#pragma unroll
            for (int rg = 0; rg < 16; ++rg)
                sa[rg] = sa[rg] * 0.125f + Msk[32 * t + rof(rg, lb)];
            float cm = sa[0];
#pragma unroll
            for (int rg = 1; rg < 16; ++rg) cm = fmaxf(cm, sa[rg]);
            cm = fmaxf(cm, __shfl_xor(cm, 32));
            if (!__all(cm <= m_run + 8.f)) {
                float mn = fmaxf(m_run, cm);
                float alpha = __expf(m_run - mn);
#pragma unroll
                for (int dt = 0; dt < 2; ++dt)
#pragma unroll
                    for (int r = 0; r < 16; ++r) cacc[dt][r] *= alpha;
                l_run *= alpha;
                m_run = mn;
            }
            float ts = 0.f;
#pragma unroll
            for (int rg = 0; rg < 16; ++rg) { sa[rg] = __expf(sa[rg] - m_run); ts += sa[rg]; }
            ts += __shfl_xor(ts, 32);
            l_run += ts;
            // P -> bf16 B-fragments (half-exchange), PV accumulate
#pragma unroll
            for (int k2 = 0; k2 < 2; ++k2) {
                unsigned int x0 = pk2(sa[8 * k2 + 0], sa[8 * k2 + 1]);
                unsigned int x1 = pk2(sa[8 * k2 + 2], sa[8 * k2 + 3]);
                unsigned int x2 = pk2(sa[8 * k2 + 4], sa[8 * k2 + 5]);
                unsigned int x3 = pk2(sa[8 * k2 + 6], sa[8 * k2 + 7]);
                unsigned int y0 = (unsigned int)__shfl_xor((int)x0, 32);
                unsigned int y1 = (unsigned int)__shfl_xor((int)x1, 32);
                unsigned int y2 = (unsigned int)__shfl_xor((int)x2, 32);
                unsigned int y3 = (unsigned int)__shfl_xor((int)x3, 32);
                union { unsigned int u[4]; su8 s; } pu;
                pu.u[0] = lb ? y2 : x0; pu.u[1] = lb ? y3 : x1;
                pu.u[2] = lb ? x2 : y0; pu.u[3] = lb ? x3 : y1;
#pragma unroll
                for (int dt = 0; dt < 2; ++dt) {
                    int vr = dt * 32 + li;
                    int vo = 32 * t + k2 * 16 + lb * 8;
                    su8 vf = *(const su8*)(&Vsm[vr * 64 + (vo ^ ((vr & 7) << 3))]);
                    mfma(cacc[dt], vf, pu.s);   // ctx^T += V^T · P^T
                }
            }
        }
        E0 -= 64;
    }
    float inv = 1.0f / l_run;
    size_t obase = (size_t)(bb * 1024 + l0 + li) * 1024 + h * 64;
#pragma unroll
    for (int dt = 0; dt < 2; ++dt)
#pragma unroll
        for (int rg = 0; rg < 16; ++rg)
            out[obase + dt * 32 + rof(rg, lb)] = cacc[dt][rg] * inv;
}

extern "C" void kernel_launch(void* const* d_in, const int* in_sizes, int n_in,
                              void* d_out, int out_size, void* d_ws, size_t ws_size,
                              hipStream_t stream) {
    const float* hs   = (const float*)d_in[0];
    const float* mask = (const float*)d_in[1];
    const float* Wq   = (const float*)d_in[2];
    const float* bq   = (const float*)d_in[3];
    const float* de   = (const float*)d_in[4];
    float* out = (float*)d_out;
    char* ws = (char*)d_ws;
    unsigned short* Ah  = (unsigned short*)(ws);               // 16 MiB
    unsigned short* Wt  = (unsigned short*)(ws + 16777216);    //  6 MiB
    unsigned short* Qw  = (unsigned short*)(ws + 23068672);    // 16 MiB
    unsigned short* Kw  = (unsigned short*)(ws + 39845888);    // 16 MiB
    unsigned short* Vtw = (unsigned short*)(ws + 56623104);    // 16 MiB
    unsigned short* Ebf = (unsigned short*)(ws + 73400320);    // 256 KiB (2048x64 bf16)

    hipLaunchKernelGGL(cvt_hidden, dim3(8192), dim3(256), 0, stream,
                       (const float4*)hs, (u16x4*)Ah);
    hipLaunchKernelGGL(cvt_w, dim3(768), dim3(256), 0, stream, Wq, Wt);
    hipLaunchKernelGGL(cvt_e, dim3(512), dim3(256), 0, stream, de, Ebf);
    hipLaunchKernelGGL(gemm_qkv, dim3(1536), dim3(256), 0, stream, Ah, Wt, bq, Qw, Kw, Vtw);
    hipLaunchKernelGGL(attn, dim3(1024), dim3(256), 0, stream, Qw, Kw, Vtw, Ebf, mask, out);
}

// Round 11
// 326.367 us; speedup vs baseline: 2.2363x; 2.2363x over previous
//
#include <hip/hip_runtime.h>
#include <stdint.h>

#define B_   8
#define S_   1024
#define D_   1024
#define H_   16
#define DH_  64
#define N3_  3072

typedef __attribute__((ext_vector_type(16))) float f32x16;
typedef __attribute__((ext_vector_type(8)))  short su8;          // 8 bf16 payload (4 VGPRs)
typedef __attribute__((ext_vector_type(8)))  unsigned short u16x8;
typedef __attribute__((ext_vector_type(4)))  unsigned short u16x4;

__device__ __forceinline__ unsigned short f2bf(float f) {
    union { float f; uint32_t u; } v; v.f = f;
    uint32_t r = v.u + 0x7fffu + ((v.u >> 16) & 1u);   // RNE
    return (unsigned short)(r >> 16);
}
__device__ __forceinline__ unsigned int pk2(float a, float b) {
    return (unsigned int)f2bf(a) | ((unsigned int)f2bf(b) << 16);
}
__device__ __forceinline__ void mfma(f32x16& d, su8 a, su8 b) {
    d = __builtin_amdgcn_mfma_f32_32x32x16_bf16(a, b, d, 0, 0, 0);
}
// C/D layout for 32x32 MFMA: col = lane&31, row = (reg&3) + 8*(reg>>2) + 4*(lane>>5)
__device__ __forceinline__ int rof(int rg, int lb) { return (rg & 3) + 8 * (rg >> 2) + 4 * lb; }

__device__ __forceinline__ void gl_lds(const unsigned short* g, unsigned short* l) {
    __builtin_amdgcn_global_load_lds(
        (const __attribute__((address_space(1))) void*)g,
        (__attribute__((address_space(3))) void*)l, 16, 0, 0);
}

// ---------------- kernel 1: hidden fp32 -> bf16 (linear) ----------------
__global__ __launch_bounds__(256) void cvt_hidden(const float4* __restrict__ src,
                                                  u16x4* __restrict__ dst) {
    int i = blockIdx.x * 256 + threadIdx.x;
    float4 v = src[i];
    u16x4 o;
    o[0] = f2bf(v.x); o[1] = f2bf(v.y); o[2] = f2bf(v.z); o[3] = f2bf(v.w);
    dst[i] = o;
}

// ---------------- kernel 2: W (k,n) fp32 -> Wt (n,k) bf16, LDS tile transpose --
__global__ __launch_bounds__(256) void cvt_w(const float* __restrict__ W,
                                             unsigned short* __restrict__ Wt) {
    __shared__ float tile[64][65];
    int bn = blockIdx.x % 48, bk = blockIdx.x / 48;
    int tr = threadIdx.x >> 4;
    int tc4 = (threadIdx.x & 15) * 4;
#pragma unroll
    for (int p = 0; p < 4; ++p) {
        int r = p * 16 + tr;
        float4 v = *(const float4*)(W + (size_t)(bk * 64 + r) * N3_ + bn * 64 + tc4);
        tile[r][tc4] = v.x; tile[r][tc4 + 1] = v.y; tile[r][tc4 + 2] = v.z; tile[r][tc4 + 3] = v.w;
    }
    __syncthreads();
#pragma unroll
    for (int p = 0; p < 4; ++p) {
        int nr = p * 16 + tr;
        u16x4 o;
        o[0] = f2bf(tile[tc4 + 0][nr]); o[1] = f2bf(tile[tc4 + 1][nr]);
        o[2] = f2bf(tile[tc4 + 2][nr]); o[3] = f2bf(tile[tc4 + 3][nr]);
        *(u16x4*)(Wt + (size_t)(bn * 64 + nr) * 1024 + bk * 64 + tc4) = o;
    }
}

// ---------------- kernel 2b: dist_emb fp32 -> bf16 (2047x64; row 2047 = pad) ---
__global__ __launch_bounds__(256) void cvt_e(const float* __restrict__ de,
                                             unsigned short* __restrict__ Ebf) {
    int i = blockIdx.x * 256 + threadIdx.x;
    if (i < 2047 * 64) Ebf[i] = f2bf(de[i]);
}

// ---------------- kernel 3: QKV GEMM (8192x3072x1024 bf16) ----------------
__global__ __launch_bounds__(256, 2) void gemm_qkv(
    const unsigned short* __restrict__ Ah, const unsigned short* __restrict__ Wt,
    const float* __restrict__ bias, unsigned short* __restrict__ Qw,
    unsigned short* __restrict__ Kw, unsigned short* __restrict__ Vtw) {
    __shared__ unsigned short Asm[2][128 * 64];
    __shared__ unsigned short Bsm[2][128 * 64];
    int tid = threadIdx.x;
    int m0 = (blockIdx.x / 24) * 128;
    int n0 = (blockIdx.x % 24) * 128;
    int w = tid >> 6, lane = tid & 63, li = lane & 31, lb = lane >> 5;
    int wm = w >> 1, wn = w & 1;

    f32x16 acc[2][2];
#pragma unroll
    for (int a = 0; a < 2; ++a)
#pragma unroll
        for (int b = 0; b < 2; ++b)
#pragma unroll
            for (int r = 0; r < 16; ++r) acc[a][b][r] = 0.f;

    int row[4], scol[4], lbase[4];
#pragma unroll
    for (int it = 0; it < 4; ++it) {
        int c = tid + it * 256;
        row[it]  = c >> 3;
        scol[it] = ((c & 7) * 8) ^ ((row[it] & 7) << 3);      // inverse-swizzled source
        lbase[it] = it * 2048 + ((tid >> 6) << 9);
    }

#pragma unroll
    for (int it = 0; it < 4; ++it) {
        gl_lds(Ah + (size_t)(m0 + row[it]) * 1024 + scol[it], &Asm[0][lbase[it]]);
        gl_lds(Wt + (size_t)(n0 + row[it]) * 1024 + scol[it], &Bsm[0][lbase[it]]);
    }
    __syncthreads();

#pragma unroll 1
    for (int t = 0; t < 16; ++t) {
        int buf = t & 1;
        if (t < 15) {
            int kb = (t + 1) * 64;
#pragma unroll
            for (int it = 0; it < 4; ++it) {
                gl_lds(Ah + (size_t)(m0 + row[it]) * 1024 + kb + scol[it], &Asm[buf ^ 1][lbase[it]]);
                gl_lds(Wt + (size_t)(n0 + row[it]) * 1024 + kb + scol[it], &Bsm[buf ^ 1][lbase[it]]);
            }
        }
#pragma unroll
        for (int kk = 0; kk < 4; ++kk) {
            su8 af[2], bf[2];
#pragma unroll
            for (int mt = 0; mt < 2; ++mt) {
                int ar = wm * 64 + mt * 32 + li;
                af[mt] = *(const su8*)(&Asm[buf][ar * 64 + ((kk * 16 + lb * 8) ^ ((ar & 7) << 3))]);
                int br = wn * 64 + mt * 32 + li;
                bf[mt] = *(const su8*)(&Bsm[buf][br * 64 + ((kk * 16 + lb * 8) ^ ((br & 7) << 3))]);
            }
            mfma(acc[0][0], af[0], bf[0]); mfma(acc[0][1], af[0], bf[1]);
            mfma(acc[1][0], af[1], bf[0]); mfma(acc[1][1], af[1], bf[1]);
        }
        __syncthreads();
    }

    // epilogue: Q/K direct (64B-coalesced); V via per-wave LDS transpose -> coalesced rows
    float* tw = (float*)(&Asm[0][0]) + w * 1056;    // 32x33 f32 per wave (Asm free now)
#pragma unroll
    for (int mt = 0; mt < 2; ++mt)
#pragma unroll
        for (int nt = 0; nt < 2; ++nt) {
            int nbase = n0 + wn * 64 + nt * 32;      // 32-aligned: single category
            int cat = (nbase % 192) >> 6;            // 0=Q,1=K,2=V
            int h = nbase / 192;
            int mbase = m0 + wm * 64 + mt * 32;
            size_t bh = (size_t)((mbase >> 10) * 16 + h);
            if (cat < 2) {
#pragma unroll
                for (int rg = 0; rg < 16; ++rg) {
                    int m = mbase + rof(rg, lb);
                    int n = nbase + li;
                    float v = acc[mt][nt][rg] + bias[n];
                    int s = m & 1023;
                    int t3 = n % 192;
                    unsigned short bv = f2bf(v);
                    if (cat == 0) Qw[bh * 65536 + s * 64 + t3] = bv;
                    else          Kw[bh * 65536 + s * 64 + (t3 - 64)] = bv;
                }
            } else {
                int dbase = nbase % 192 - 128;       // 0 or 32
#pragma unroll
                for (int rg = 0; rg < 16; ++rg)
                    tw[rof(rg, lb) * 33 + li] = acc[mt][nt][rg] + bias[nbase + li];
                int sb = (mbase & 1023) + li;
#pragma unroll
                for (int j2 = 0; j2 < 16; ++j2) {
                    int jd = j2 * 2 + lb;
                    float v = tw[li * 33 + jd];
                    Vtw[bh * 65536 + (size_t)(dbase + jd) * 1024 + sb] = f2bf(v);
                }
            }
        }
}

// ---------------- kernel 4: fused attention (E reg-prefetched; NO tight VGPR cap) --
// grid = 128 (bh) * 8 (q-blocks of 128 rows); 4 waves, wave = 32 q-rows.
// LDS 50.7 KB allows 3 blocks/CU; (256,2) leaves allocator free (r9: (256,3) capped
// VGPR at 84 -> 337 MB scratch writes, 2.2x slowdown).
__global__ __launch_bounds__(256, 2) void attn(
    const unsigned short* __restrict__ Qw, const unsigned short* __restrict__ Kw,
    const unsigned short* __restrict__ Vtw, const unsigned short* __restrict__ Ebf,
    const float* __restrict__ mask, float* __restrict__ out) {
    __shared__ unsigned short Ksm[64 * 64];     // 8 KB, swizzled [r][d]
    __shared__ unsigned short Vsm[64 * 64];     // 8 KB, swizzled [d][r]
    __shared__ float Tsm[4][2112];              // 33 KB, per-wave diag buffer (stride 33)
    __shared__ float Msk[64];                   // current-tile mask slice

    int tid = threadIdx.x;
    int bh = blockIdx.x >> 3, qb = blockIdx.x & 7;
    int bb = bh >> 4, h = bh & 15;
    int l0b = qb << 7;
    int w = tid >> 6, lane = tid & 63, li = lane & 31, lb = lane >> 5;
    int l0 = l0b + 32 * w;

    su8 qf[4];
#pragma unroll
    for (int kk = 0; kk < 4; ++kk)
        qf[kk] = *(const su8*)(Qw + (size_t)(bh * 1024 + l0 + li) * 64 + lb * 8 + kk * 16);

    f32x16 cacc[2];
#pragma unroll
    for (int dt = 0; dt < 2; ++dt)
#pragma unroll
        for (int r = 0; r < 16; ++r) cacc[dt][r] = 0.f;
    float m_run = -1e30f, l_run = 0.f;

    // T14 prefetch: K/V/mask for current tile in regs
    u16x8 kpre[2], vpre[2];
    float mpre = 0.f;
    int pc_row[2], pc_o8[2];
#pragma unroll
    for (int it = 0; it < 2; ++it) {
        int c = tid + it * 256;
        pc_row[it] = c >> 3; pc_o8[it] = (c & 7) * 8;
    }
#pragma unroll
    for (int it = 0; it < 2; ++it) {
        kpre[it] = *(const u16x8*)(Kw + (size_t)bh * 65536 + (size_t)pc_row[it] * 64 + pc_o8[it]);
        vpre[it] = *(const u16x8*)(Vtw + (size_t)bh * 65536 + (size_t)pc_row[it] * 1024 + pc_o8[it]);
    }
    if (tid < 64) mpre = mask[bb * 1024 + tid];

    // E fragments for phase (ss=0, t=0), offw = 32w+32
    int E0 = l0b + 960;
    su8 eb[8];
    {
        const unsigned short* ebase = Ebf + ((size_t)(E0 + 32 * w + 32 + li) << 6) + lb * 8;
#pragma unroll
        for (int ct = 0; ct < 2; ++ct)
#pragma unroll
            for (int kk = 0; kk < 4; ++kk)
                eb[ct * 4 + kk] = *(const su8*)(ebase + ct * 2048 + kk * 16);
    }

#pragma unroll 1
    for (int ss = 0; ss < 16; ++ss) {
        int r0s = ss * 64;
        __syncthreads();
#pragma unroll
        for (int it = 0; it < 2; ++it) {
            int row = pc_row[it], o8 = pc_o8[it];
            int lidx = row * 64 + (o8 ^ ((row & 7) << 3));
            *(u16x8*)(&Ksm[lidx]) = kpre[it];
            *(u16x8*)(&Vsm[lidx]) = vpre[it];
        }
        if (tid < 64) Msk[tid] = mpre;
        __syncthreads();
        if (ss < 15) {   // prefetch next tile's K/V/mask
            int r0n = r0s + 64;
#pragma unroll
            for (int it = 0; it < 2; ++it) {
                int row = pc_row[it], o8 = pc_o8[it];
                kpre[it] = *(const u16x8*)(Kw + (size_t)bh * 65536 + (size_t)(r0n + row) * 64 + o8);
                vpre[it] = *(const u16x8*)(Vtw + (size_t)bh * 65536 + (size_t)row * 1024 + r0n + o8);
            }
            if (tid < 64) mpre = mask[bb * 1024 + r0n + tid];
        }

#pragma unroll
        for (int t = 0; t < 2; ++t) {
            su8 kf[4];
#pragma unroll
            for (int kk = 0; kk < 4; ++kk) {
                int kr = 32 * t + li;
                kf[kk] = *(const su8*)(&Ksm[kr * 64 + ((kk * 16 + lb * 8) ^ ((kr & 7) << 3))]);
            }
            f32x16 sa;
#pragma unroll
            for (int r = 0; r < 16; ++r) sa[r] = 0.f;
#pragma unroll
            for (int kk = 0; kk < 4; ++kk) mfma(sa, kf[kk], qf[kk]);   // S^T = K·Q^T

            // T_q: E (regs) · Q -> Tsm (stride 33) -> diagonal gather
#pragma unroll
            for (int ct = 0; ct < 2; ++ct) {
                f32x16 fa;
#pragma unroll
                for (int r = 0; r < 16; ++r) fa[r] = 0.f;
#pragma unroll
                for (int kk = 0; kk < 4; ++kk) mfma(fa, eb[ct * 4 + kk], qf[kk]);
#pragma unroll
                for (int rg = 0; rg < 16; ++rg)
                    Tsm[w][(ct * 32 + rof(rg, lb)) * 33 + li] = fa[rg];
            }
#pragma unroll
            for (int rg = 0; rg < 16; ++rg) {
                int rt = rof(rg, lb);
                sa[rg] += Tsm[w][(li - rt + 31) * 33 + li];
            }
            // T_k: same E fragments · K -> Tsm -> gather
#pragma unroll
            for (int ct = 0; ct < 2; ++ct) {
                f32x16 fa;
#pragma unroll
                for (int r = 0; r < 16; ++r) fa[r] = 0.f;
#pragma unroll
                for (int kk = 0; kk < 4; ++kk) mfma(fa, eb[ct * 4 + kk], kf[kk]);
#pragma unroll
                for (int rg = 0; rg < 16; ++rg)
                    Tsm[w][(ct * 32 + rof(rg, lb)) * 33 + li] = fa[rg];
            }
#pragma unroll
            for (int rg = 0; rg < 16; ++rg) {
                int rt = rof(rg, lb);
                sa[rg] += Tsm[w][(li - rt + 31) * 33 + rt];
            }
            // issue next-phase E loads (eb dead after last Tk mfma; latency hides under softmax+PV)
            if (ss < 15 || t == 0) {
                int E0n  = (t == 0) ? E0 : (E0 - 64);
                int offn = (t == 0) ? (32 * w) : (32 * w + 32);
                const unsigned short* ebase = Ebf + ((size_t)(E0n + offn + li) << 6) + lb * 8;
#pragma unroll
                for (int ct = 0; ct < 2; ++ct)
#pragma unroll
                    for (int kk = 0; kk < 4; ++kk)
                        eb[ct * 4 + kk] = *(const su8*)(ebase + ct * 2048 + kk * 16);
            }
            // scale + mask + online softmax with defer-max
#pragma unroll
            for (int rg = 0; rg < 16; ++rg)
                sa[rg] = sa[rg] * 0.125f + Msk[32 * t + rof(rg, lb)];
            float cm = sa[0];
#pragma unroll
            for (int rg = 1; rg < 16; ++rg) cm = fmaxf(cm, sa[rg]);
            cm = fmaxf(cm, __shfl_xor(cm, 32));
            if (!__all(cm <= m_run + 8.f)) {
                float mn = fmaxf(m_run, cm);
                float alpha = __expf(m_run - mn);
#pragma unroll
                for (int dt = 0; dt < 2; ++dt)
#pragma unroll
                    for (int r = 0; r < 16; ++r) cacc[dt][r] *= alpha;
                l_run *= alpha;
                m_run = mn;
            }
            float ts = 0.f;
#pragma unroll
            for (int rg = 0; rg < 16; ++rg) { sa[rg] = __expf(sa[rg] - m_run); ts += sa[rg]; }
            ts += __shfl_xor(ts, 32);
            l_run += ts;
            // P -> bf16 B-fragments (half-exchange), PV accumulate
#pragma unroll
            for (int k2 = 0; k2 < 2; ++k2) {
                unsigned int x0 = pk2(sa[8 * k2 + 0], sa[8 * k2 + 1]);
                unsigned int x1 = pk2(sa[8 * k2 + 2], sa[8 * k2 + 3]);
                unsigned int x2 = pk2(sa[8 * k2 + 4], sa[8 * k2 + 5]);
                unsigned int x3 = pk2(sa[8 * k2 + 6], sa[8 * k2 + 7]);
                unsigned int y0 = (unsigned int)__shfl_xor((int)x0, 32);
                unsigned int y1 = (unsigned int)__shfl_xor((int)x1, 32);
                unsigned int y2 = (unsigned int)__shfl_xor((int)x2, 32);
                unsigned int y3 = (unsigned int)__shfl_xor((int)x3, 32);
                union { unsigned int u[4]; su8 s; } pu;
                pu.u[0] = lb ? y2 : x0; pu.u[1] = lb ? y3 : x1;
                pu.u[2] = lb ? x2 : y0; pu.u[3] = lb ? x3 : y1;
#pragma unroll
                for (int dt = 0; dt < 2; ++dt) {
                    int vr = dt * 32 + li;
                    int vo = 32 * t + k2 * 16 + lb * 8;
                    su8 vf = *(const su8*)(&Vsm[vr * 64 + (vo ^ ((vr & 7) << 3))]);
                    mfma(cacc[dt], vf, pu.s);   // ctx^T += V^T · P^T
                }
            }
        }
        E0 -= 64;
    }
    float inv = 1.0f / l_run;
    size_t obase = (size_t)(bb * 1024 + l0 + li) * 1024 + h * 64;
#pragma unroll
    for (int dt = 0; dt < 2; ++dt)
#pragma unroll
        for (int rg = 0; rg < 16; ++rg)
            out[obase + dt * 32 + rof(rg, lb)] = cacc[dt][rg] * inv;
}

extern "C" void kernel_launch(void* const* d_in, const int* in_sizes, int n_in,
                              void* d_out, int out_size, void* d_ws, size_t ws_size,
                              hipStream_t stream) {
    const float* hs   = (const float*)d_in[0];
    const float* mask = (const float*)d_in[1];
    const float* Wq   = (const float*)d_in[2];
    const float* bq   = (const float*)d_in[3];
    const float* de   = (const float*)d_in[4];
    float* out = (float*)d_out;
    char* ws = (char*)d_ws;
    unsigned short* Ah  = (unsigned short*)(ws);               // 16 MiB
    unsigned short* Wt  = (unsigned short*)(ws + 16777216);    //  6 MiB
    unsigned short* Qw  = (unsigned short*)(ws + 23068672);    // 16 MiB
    unsigned short* Kw  = (unsigned short*)(ws + 39845888);    // 16 MiB
    unsigned short* Vtw = (unsigned short*)(ws + 56623104);    // 16 MiB
    unsigned short* Ebf = (unsigned short*)(ws + 73400320);    // 256 KiB (2048x64 bf16)

    hipLaunchKernelGGL(cvt_hidden, dim3(8192), dim3(256), 0, stream,
                       (const float4*)hs, (u16x4*)Ah);
    hipLaunchKernelGGL(cvt_w, dim3(768), dim3(256), 0, stream, Wq, Wt);
    hipLaunchKernelGGL(cvt_e, dim3(512), dim3(256), 0, stream, de, Ebf);
    hipLaunchKernelGGL(gemm_qkv, dim3(1536), dim3(256), 0, stream, Ah, Wt, bq, Qw, Kw, Vtw);
    hipLaunchKernelGGL(attn, dim3(1024), dim3(256), 0, stream, Qw, Kw, Vtw, Ebf, mask, out);
}